// Round 15
// baseline (360.450 us; speedup 1.0000x reference)
//
#include <hip/hip_runtime.h>

#define T_TOK 512
#define HDIM 2048
#define NEXP 8
#define IDIM 4096

typedef float f32x4 __attribute__((ext_vector_type(4)));
typedef __bf16 bf16x8 __attribute__((ext_vector_type(8)));
typedef unsigned short ushort8 __attribute__((ext_vector_type(8)));

static __device__ __forceinline__ unsigned short f2bf(float f) {
    unsigned int u = __float_as_uint(f);
    u = (u + 0x7fffu + ((u >> 16) & 1u)) >> 16;
    return (unsigned short)u;
}

static __device__ __forceinline__ bf16x8 cvt8(const f32x4 lo, const f32x4 hi) {
    bf16x8 r;
#pragma unroll
    for (int q = 0; q < 4; ++q) { r[q] = (__bf16)lo[q]; r[q + 4] = (__bf16)hi[q]; }
    return r;
}

// async global->LDS, 16 B/lane; LDS dest = wave-uniform base + lane*16,
// global source is PER-LANE (carries the granule swizzle)
static __device__ __forceinline__ void gload_lds16(const void* g, void* l) {
    auto gp = reinterpret_cast<const unsigned int __attribute__((address_space(1)))*>(
        reinterpret_cast<unsigned long long>(g));
    auto lp = reinterpret_cast<unsigned int __attribute__((address_space(3)))*>(
        static_cast<unsigned int>(reinterpret_cast<unsigned long long>(l)));
    __builtin_amdgcn_global_load_lds(gp, lp, 16, 0, 0);
}

// non-temporal: single-use weight stream, keep OUT of L3 (r14: confirmed ~2x
// on the HBM miss stream; also keeps w2 L3-resident for k_moe2)
static __device__ __forceinline__ void gload_lds16_nt(const void* g, void* l) {
    auto gp = reinterpret_cast<const unsigned int __attribute__((address_space(1)))*>(
        reinterpret_cast<unsigned long long>(g));
    auto lp = reinterpret_cast<unsigned int __attribute__((address_space(3)))*>(
        static_cast<unsigned int>(reinterpret_cast<unsigned long long>(l)));
    __builtin_amdgcn_global_load_lds(gp, lp, 16, 0, 2 /*NT*/);
}

// ---------------- routing ------------------------------------------------------
__global__ void k_route(const float* __restrict__ logits,
                        int* __restrict__ off, int* __restrict__ tok,
                        float* __restrict__ scale) {
    __shared__ int cnt[NEXP], cur[NEXP];
    const int t = threadIdx.x;
    if (t < NEXP) cnt[t] = 0;
    __syncthreads();
    float m = logits[t * NEXP];
    int a = 0;
#pragma unroll
    for (int j = 1; j < NEXP; ++j) {
        float v = logits[t * NEXP + j];
        if (v > m) { m = v; a = j; }
    }
    scale[t] = 1.f / (1.f + __expf(-m));
    atomicAdd(&cnt[a], 1);
    __syncthreads();
    if (t == 0) {
        int o = 0;
        for (int e = 0; e < NEXP; ++e) { off[e] = o; cur[e] = o; o += cnt[e]; }
        off[NEXP] = o;
    }
    __syncthreads();
    int r = atomicAdd(&cur[a], 1);
    tok[r] = t;
}

// ---------------- gather + scale + bf16 ---------------------------------------
__global__ void k_gather(const float* __restrict__ x, const int* __restrict__ tok,
                         const float* __restrict__ scale,
                         unsigned short* __restrict__ xs) {
    const int pos = blockIdx.x;
    const int t = tok[pos];
    const float s = scale[t];
    const int c = threadIdx.x * 8;
    const float4* src = (const float4*)(x + (size_t)t * HDIM + c);
    float4 v0 = src[0], v1 = src[1];
    ushort8 o;
    o[0] = f2bf(v0.x * s); o[1] = f2bf(v0.y * s);
    o[2] = f2bf(v0.z * s); o[3] = f2bf(v0.w * s);
    o[4] = f2bf(v1.x * s); o[5] = f2bf(v1.y * s);
    o[6] = f2bf(v1.z * s); o[7] = f2bf(v1.w * s);
    *(ushort8*)(xs + (size_t)pos * HDIM + c) = o;
}

// ---------------- GEMM1: gate/up + SiLU — sequential per-block weight stream ---
// 4096 blocks: expert = bid&7 (XCD cluster), ntile = bid>>3 (512 tiles of BN=8).
// Block footprint: w1 rows n0..n0+7 (32KB contiguous) + w3 same — read strictly
// row-by-row, sequential, NT. One MFMA B-frag = cols 0-7 w1 | cols 8-15 w3, so
// gate and up come from the SAME MFMA (zero waste); epilogue pairs via shfl_xor 8.
// 256 thr = 4 waves, each M=32 (2 m-frags); block M=128. LDS 64K: 16 slabs x 4KB
// (half-rows; 2 K-passes of 1024). A (xs, L2-hot) direct to registers.
__global__ void __launch_bounds__(256, 2)
k_moe1(const unsigned short* __restrict__ xs,
       const float* __restrict__ w1,
       const float* __restrict__ w3,
       const int* __restrict__ off,
       unsigned short* __restrict__ hbuf) {
    __shared__ char smem[65536];

    const int tid = threadIdx.x;
    const int w = tid >> 6, l = tid & 63;
    const int e = blockIdx.x & 7;
    const int n0 = (blockIdx.x >> 3) * 8;
    const int pos_beg = off[e], pos_end = off[e + 1];

    const char* w1b = (const char*)(w1 + (size_t)e * IDIM * HDIM);
    const char* w3b = (const char*)(w3 + (size_t)e * IDIM * HDIM);

    for (int m0 = pos_beg; m0 < pos_end; m0 += 128) {
        // A fragment pointers: wave w rows m0 + w*32 + fm*16 + (l&15)
        const unsigned short* pA[2];
#pragma unroll
        for (int fm = 0; fm < 2; ++fm) {
            int gr = m0 + w * 32 + fm * 16 + (l & 15);
            if (gr > T_TOK - 1) gr = T_TOK - 1;
            pA[fm] = xs + (size_t)gr * HDIM + (l >> 4) * 8;
        }

        f32x4 acc[2];
        acc[0] = (f32x4){0, 0, 0, 0};
        acc[1] = (f32x4){0, 0, 0, 0};

#pragma unroll 1
        for (int ko = 0; ko < 2; ++ko) {
            // stage 16 half-rows (4KB each), strictly sequential per row, NT.
            // slab ridx: 0-7 = w1 rows n0+ridx, 8-15 = w3 rows n0+ridx-8.
            // granule swizzle: LDS granule p holds global granule
            // (p&~7)|((p&7)^s), s = ridx&7  -> conflict-free read below.
#pragma unroll
            for (int j = 0; j < 4; ++j) {
                const int ridx = w * 4 + j;
                const int s = ridx & 7;
                const char* rb = (ridx < 8)
                    ? w1b + (size_t)(n0 + ridx) * (HDIM * 4)
                    : w3b + (size_t)(n0 + ridx - 8) * (HDIM * 4);
                const int lg = (l & 56) | ((l & 7) ^ s);   // swizzled src granule
#pragma unroll
                for (int c = 0; c < 4; ++c) {
                    gload_lds16_nt(rb + ko * 4096 + ((c * 64 + lg) << 4),
                                   smem + ridx * 4096 + c * 1024);
                }
            }
            asm volatile("s_waitcnt vmcnt(0)" ::: "memory");
            __syncthreads();

            // compute: 32 k-steps of 32 over this 1024-wide chunk
            const int ridx = l & 15;
            const int s = ridx & 7;
            const char* sb = smem + ridx * 4096;
#pragma unroll 4
            for (int kk = 0; kk < 32; ++kk) {
                const int g0 = kk * 8 + (l >> 4) * 2;
                const int g1 = g0 + 1;
                f32x4 b0 = *(const f32x4*)(sb + (((g0 & ~7) | ((g0 & 7) ^ s)) << 4));
                f32x4 b1 = *(const f32x4*)(sb + (((g1 & ~7) | ((g1 & 7) ^ s)) << 4));
                bf16x8 bb = cvt8(b0, b1);
#pragma unroll
                for (int fm = 0; fm < 2; ++fm) {
                    bf16x8 a = *(const bf16x8*)(pA[fm] + ko * 1024 + kk * 32);
                    acc[fm] = __builtin_amdgcn_mfma_f32_16x16x32_bf16(
                        a, bb, acc[fm], 0, 0, 0);
                }
            }
            __syncthreads();
        }

        // epilogue: C col l&15: lanes 0-7 hold gate(col n0+l&7), 8-15 hold up.
        // pair via shfl_xor 8; lanes 0-7 write h. C row = (l>>4)*4 + r.
#pragma unroll
        for (int fm = 0; fm < 2; ++fm)
#pragma unroll
            for (int r = 0; r < 4; ++r) {
                const float own = acc[fm][r];
                const float oth = __shfl_xor(own, 8);
                const float gate = (l & 8) ? oth : own;
                const float up   = (l & 8) ? own : oth;
                const float hv = gate / (1.f + __expf(-gate)) * up;
                const int pos = m0 + w * 32 + fm * 16 + (l >> 4) * 4 + r;
                if (!(l & 8) && pos < pos_end)
                    hbuf[(size_t)pos * IDIM + n0 + (l & 7)] = f2bf(hv);
            }
    }
}

// ---------------- GEMM2: down proj + scatter (unchanged r14; w2 L3-warm) -------
__global__ void __launch_bounds__(256, 4)
k_moe2(const unsigned short* __restrict__ hbuf,
       const float* __restrict__ w2,
       const int* __restrict__ off,
       const int* __restrict__ tok,
       float* __restrict__ out) {
    __shared__ char smem[20480];

    const int tid = threadIdx.x;
    const int w = tid >> 6, l = tid & 63;
    const int e = blockIdx.x & 7;
    const int n0 = (blockIdx.x >> 3) * 16;
    const int ks0 = (blockIdx.x * 13) & 63;
    const int pos_beg = off[e], pos_end = off[e + 1];
    const char* w2b = (const char*)(w2 + (size_t)e * HDIM * IDIM);
    const char* hb  = (const char*)hbuf;

    const int ia = w * 4;
    const int arow_off = l >> 3;
    const int asw = ((l & 7) ^ (l >> 3)) << 4;
    const int brow_off = l >> 4;

    for (int m0 = pos_beg; m0 < pos_end; m0 += 128) {
        f32x4 acc[2];
        acc[0] = (f32x4){0, 0, 0, 0};
        acc[1] = (f32x4){0, 0, 0, 0};

#pragma unroll 1
        for (int it = 0; it < IDIM / 64; ++it) {
            const int ks = (it + ks0) & 63;
            const int k0 = ks * 64;
#pragma unroll
            for (int j = 0; j < 4; ++j) {
                const int i = ia + j;
                int gr = m0 + i * 8 + arow_off; if (gr > T_TOK - 1) gr = T_TOK - 1;
                gload_lds16(hb + (size_t)gr * (IDIM * 2) + k0 * 2 + asw, smem + i * 1024);
            }
            {
                const int r = w * 4 + brow_off;
                const size_t so = (size_t)(n0 + r) * (IDIM * 4) + k0 * 4 +
                                  (((l & 15) << 4) ^ ((r & 7) << 4));
                gload_lds16(w2b + so, smem + 16384 + w * 1024);
            }
            __syncthreads();

#pragma unroll
            for (int kk = 0; kk < 2; ++kk) {
                const int rB = l & 15;
                const int p0 = (kk * 128 + ((l >> 4) << 5)) ^ ((l & 7) << 4);
                const char* pb = smem + 16384 + rB * 256;
                f32x4 b0 = *(const f32x4*)(pb + p0);
                f32x4 b1 = *(const f32x4*)(pb + (p0 ^ 16));
                bf16x8 bb = cvt8(b0, b1);
#pragma unroll
                for (int fm = 0; fm < 2; ++fm) {
                    const int row = w * 32 + fm * 16 + (l & 15);
                    const int kb = (kk * 64 + ((l >> 4) << 4)) ^ ((l & 7) << 4);
                    bf16x8 a = *(const bf16x8*)(smem + row * 128 + kb);
                    acc[fm] = __builtin_amdgcn_mfma_f32_16x16x32_bf16(a, bb, acc[fm], 0, 0, 0);
                }
            }
            __syncthreads();
        }

#pragma unroll
        for (int fm = 0; fm < 2; ++fm)
#pragma unroll
            for (int r = 0; r < 4; ++r) {
                const int pos = m0 + w * 32 + fm * 16 + (l >> 4) * 4 + r;
                if (pos < pos_end) {
                    const int t = tok[pos];
                    out[(size_t)t * HDIM + n0 + (l & 15)] = acc[fm][r];
                }
            }
    }
}

extern "C" void kernel_launch(void* const* d_in, const int* in_sizes, int n_in,
                              void* d_out, int out_size, void* d_ws, size_t ws_size,
                              hipStream_t stream) {
    const float* x      = (const float*)d_in[0];
    const float* logits = (const float*)d_in[1];
    const float* w1     = (const float*)d_in[2];
    const float* w3     = (const float*)d_in[3];
    const float* w2     = (const float*)d_in[4];
    float* out = (float*)d_out;

    char* ws = (char*)d_ws;
    int* off   = (int*)ws;                          // 9 ints
    int* tok   = (int*)(ws + 64);                   // 512 ints
    float* scl = (float*)(ws + 64 + 2048);          // 512 floats
    unsigned short* xs   = (unsigned short*)(ws + 8192);                             // 2 MiB
    unsigned short* hbuf = (unsigned short*)(ws + 8192 + (size_t)T_TOK * HDIM * 2);  // 4 MiB

    k_route<<<1, T_TOK, 0, stream>>>(logits, off, tok, scl);
    k_gather<<<T_TOK, 256, 0, stream>>>(x, tok, scl, xs);
    k_moe1<<<NEXP * (IDIM / 8), 256, 0, stream>>>(xs, w1, w3, off, hbuf);
    k_moe2<<<NEXP * (HDIM / 16), 256, 0, stream>>>(hbuf, w2, off, tok, out);
}

// Round 16
// 176.119 us; speedup vs baseline: 2.0466x; 2.0466x over previous
//
#include <hip/hip_runtime.h>

#define T_TOK 512
#define HDIM 2048
#define NEXP 8
#define IDIM 4096

typedef float f32x4 __attribute__((ext_vector_type(4)));
typedef __bf16 bf16x8 __attribute__((ext_vector_type(8)));
typedef unsigned short ushort8 __attribute__((ext_vector_type(8)));
typedef unsigned int u32x4 __attribute__((ext_vector_type(4)));

static __device__ __forceinline__ unsigned short f2bf(float f) {
    unsigned int u = __float_as_uint(f);
    u = (u + 0x7fffu + ((u >> 16) & 1u)) >> 16;
    return (unsigned short)u;
}

static __device__ __forceinline__ bf16x8 cvt8(const f32x4 lo, const f32x4 hi) {
    bf16x8 r;
#pragma unroll
    for (int q = 0; q < 4; ++q) { r[q] = (__bf16)lo[q]; r[q + 4] = (__bf16)hi[q]; }
    return r;
}

// plain 16B vector load (the 6.3-7 TB/s path) — non-temporal for weight streams
static __device__ __forceinline__ u32x4 ntload16(const void* p) {
    return __builtin_nontemporal_load((const u32x4*)p);
}

// async global->LDS (kept for cache-warm moe2 staging)
static __device__ __forceinline__ void gload_lds16(const void* g, void* l) {
    auto gp = reinterpret_cast<const unsigned int __attribute__((address_space(1)))*>(
        reinterpret_cast<unsigned long long>(g));
    auto lp = reinterpret_cast<unsigned int __attribute__((address_space(3)))*>(
        static_cast<unsigned int>(reinterpret_cast<unsigned long long>(l)));
    __builtin_amdgcn_global_load_lds(gp, lp, 16, 0, 0);
}

// ---------------- routing ------------------------------------------------------
__global__ void k_route(const float* __restrict__ logits,
                        int* __restrict__ off, int* __restrict__ tok,
                        float* __restrict__ scale) {
    __shared__ int cnt[NEXP], cur[NEXP];
    const int t = threadIdx.x;
    if (t < NEXP) cnt[t] = 0;
    __syncthreads();
    float m = logits[t * NEXP];
    int a = 0;
#pragma unroll
    for (int j = 1; j < NEXP; ++j) {
        float v = logits[t * NEXP + j];
        if (v > m) { m = v; a = j; }
    }
    scale[t] = 1.f / (1.f + __expf(-m));
    atomicAdd(&cnt[a], 1);
    __syncthreads();
    if (t == 0) {
        int o = 0;
        for (int e = 0; e < NEXP; ++e) { off[e] = o; cur[e] = o; o += cnt[e]; }
        off[NEXP] = o;
    }
    __syncthreads();
    int r = atomicAdd(&cur[a], 1);
    tok[r] = t;
}

// ---------------- gather + scale + bf16 ---------------------------------------
__global__ void k_gather(const float* __restrict__ x, const int* __restrict__ tok,
                         const float* __restrict__ scale,
                         unsigned short* __restrict__ xs) {
    const int pos = blockIdx.x;
    const int t = tok[pos];
    const float s = scale[t];
    const int c = threadIdx.x * 8;
    const float4* src = (const float4*)(x + (size_t)t * HDIM + c);
    float4 v0 = src[0], v1 = src[1];
    ushort8 o;
    o[0] = f2bf(v0.x * s); o[1] = f2bf(v0.y * s);
    o[2] = f2bf(v0.z * s); o[3] = f2bf(v0.w * s);
    o[4] = f2bf(v1.x * s); o[5] = f2bf(v1.y * s);
    o[6] = f2bf(v1.z * s); o[7] = f2bf(v1.w * s);
    *(ushort8*)(xs + (size_t)pos * HDIM + c) = o;
}

// ---------------- GEMM1: gate/up + SiLU ----------------------------------------
// r14 structure (512 blocks: e=bid&7 XCD-clustered, BN=64; 8 waves 2x4; BK=64;
// 48K LDS; K-stagger; NT weights) with the staging path swapped:
// global_load -> VGPR -> ds_write (T14 split: next tile's loads issue BETWEEN
// barriers and fly during compute). Same addresses/swizzle as r14.
__global__ void __launch_bounds__(512, 4)
k_moe1(const unsigned short* __restrict__ xs,
       const float* __restrict__ w1,
       const float* __restrict__ w3,
       const int* __restrict__ off,
       unsigned short* __restrict__ hbuf) {
    __shared__ char smem[49152];

    const int tid = threadIdx.x;
    const int w = tid >> 6, l = tid & 63;
    const int wr = w >> 2, wc = w & 3;
    const int e = blockIdx.x & 7;
    const int n0 = (blockIdx.x >> 3) * 64;
    const int ks0 = (blockIdx.x * 13) & 31;
    const int pos_beg = off[e], pos_end = off[e + 1];

    const char* w1b = (const char*)(w1 + (size_t)e * IDIM * HDIM);
    const char* w3b = (const char*)(w3 + (size_t)e * IDIM * HDIM);
    const char* xsb = (const char*)xs;

    const int i0 = w * 2, i1 = i0 + 1;
    const int asw = ((l & 7) ^ (l >> 3)) << 4;   // A source granule swizzle
    const int r0 = i0 * 4 + (l >> 4), r1 = i1 * 4 + (l >> 4);

    // per-thread source base pointers (pre-swizzled, rule 21)
    const char* pw1_0 = w1b + (size_t)(n0 + r0) * (HDIM * 4) + (((l & 15) << 4) ^ ((r0 & 7) << 4));
    const char* pw1_1 = w1b + (size_t)(n0 + r1) * (HDIM * 4) + (((l & 15) << 4) ^ ((r1 & 7) << 4));
    const char* pw3_0 = w3b + (size_t)(n0 + r0) * (HDIM * 4) + (((l & 15) << 4) ^ ((r0 & 7) << 4));
    const char* pw3_1 = w3b + (size_t)(n0 + r1) * (HDIM * 4) + (((l & 15) << 4) ^ ((r1 & 7) << 4));

    // LDS dest (linear, lane*16 — same layout gload_lds wrote)
    u32x4* dA0  = (u32x4*)(smem + i0 * 1024 + (l << 4));
    u32x4* dA1  = (u32x4*)(smem + i1 * 1024 + (l << 4));
    u32x4* dB10 = (u32x4*)(smem + 16384 + i0 * 1024 + (l << 4));
    u32x4* dB11 = (u32x4*)(smem + 16384 + i1 * 1024 + (l << 4));
    u32x4* dB30 = (u32x4*)(smem + 32768 + i0 * 1024 + (l << 4));
    u32x4* dB31 = (u32x4*)(smem + 32768 + i1 * 1024 + (l << 4));

    for (int m0 = pos_beg; m0 < pos_end; m0 += 128) {
        int gr0 = m0 + i0 * 8 + (l >> 3); if (gr0 > T_TOK - 1) gr0 = T_TOK - 1;
        int gr1 = m0 + i1 * 8 + (l >> 3); if (gr1 > T_TOK - 1) gr1 = T_TOK - 1;
        const char* pa0 = xsb + (size_t)gr0 * (HDIM * 2) + asw;
        const char* pa1 = xsb + (size_t)gr1 * (HDIM * 2) + asw;

        f32x4 accG[4], accU[4];
#pragma unroll
        for (int i = 0; i < 4; ++i) { accG[i] = (f32x4){0,0,0,0}; accU[i] = (f32x4){0,0,0,0}; }

        u32x4 va0, va1, vb10, vb11, vb30, vb31;
#define LDREGS(IT)                                                           \
        {                                                                    \
            const int kq = (((IT) + ks0) & 31) * 64;                         \
            va0  = *(const u32x4*)(pa0 + kq * 2);                            \
            va1  = *(const u32x4*)(pa1 + kq * 2);                            \
            vb10 = ntload16(pw1_0 + kq * 4);                                 \
            vb11 = ntload16(pw1_1 + kq * 4);                                 \
            vb30 = ntload16(pw3_0 + kq * 4);                                 \
            vb31 = ntload16(pw3_1 + kq * 4);                                 \
        }

        LDREGS(0)
#pragma unroll 1
        for (int it = 0; it < 32; ++it) {
            // commit current tile to LDS
            *dA0 = va0; *dA1 = va1;
            *dB10 = vb10; *dB11 = vb11; *dB30 = vb30; *dB31 = vb31;
            __syncthreads();
            // issue NEXT tile's loads now — they fly during the MFMA phase
            if (it + 1 < 32) LDREGS(it + 1)

#pragma unroll
            for (int kk = 0; kk < 2; ++kk) {
                bf16x8 a[4];
#pragma unroll
                for (int fm = 0; fm < 4; ++fm) {
                    const int row = wr * 64 + fm * 16 + (l & 15);
                    const int kb = (kk * 64 + ((l >> 4) << 4)) ^ ((l & 7) << 4);
                    a[fm] = *(const bf16x8*)(smem + row * 128 + kb);
                }
                const int rB = wc * 16 + (l & 15);
                const int p0 = (kk * 128 + ((l >> 4) << 5)) ^ ((l & 7) << 4);
                const char* pg = smem + 16384 + rB * 256;
                const char* pu = smem + 32768 + rB * 256;
                f32x4 g0 = *(const f32x4*)(pg + p0);
                f32x4 g1 = *(const f32x4*)(pg + (p0 ^ 16));
                f32x4 u0 = *(const f32x4*)(pu + p0);
                f32x4 u1 = *(const f32x4*)(pu + (p0 ^ 16));
                bf16x8 bg = cvt8(g0, g1);
                bf16x8 bu = cvt8(u0, u1);
#pragma unroll
                for (int fm = 0; fm < 4; ++fm) {
                    accG[fm] = __builtin_amdgcn_mfma_f32_16x16x32_bf16(
                        a[fm], bg, accG[fm], 0, 0, 0);
                    accU[fm] = __builtin_amdgcn_mfma_f32_16x16x32_bf16(
                        a[fm], bu, accU[fm], 0, 0, 0);
                }
            }
            __syncthreads();   // all reads done before next ds_write overwrites
        }
#undef LDREGS

        // epilogue: h = silu(gate) * up -> bf16  (C: col=l&15, row=(l>>4)*4+r)
#pragma unroll
        for (int fm = 0; fm < 4; ++fm)
#pragma unroll
            for (int r = 0; r < 4; ++r) {
                const int pos = m0 + wr * 64 + fm * 16 + (l >> 4) * 4 + r;
                if (pos < pos_end) {
                    const float gv = accG[fm][r];
                    const float uv = accU[fm][r];
                    const float hv = gv / (1.f + __expf(-gv)) * uv;
                    hbuf[(size_t)pos * IDIM + n0 + wc * 16 + (l & 15)] = f2bf(hv);
                }
            }
    }
}

// ---------------- GEMM2: down proj + scatter -----------------------------------
// BN=32 (was 16): 512 blocks (e=bid&7, 64 ntiles), 256 thr (4 waves 2x2),
// C-tile 128x32, K=4096, BK=64, stagger. Halves hbuf L2 re-reads vs BN=16.
// w2 stays CACHED (L3-warm); hbuf L2-hot -> keep global_load_lds staging.
__global__ void __launch_bounds__(256, 4)
k_moe2(const unsigned short* __restrict__ hbuf,
       const float* __restrict__ w2,
       const int* __restrict__ off,
       const int* __restrict__ tok,
       float* __restrict__ out) {
    __shared__ char smem[24576];   // A 16K + B 8K

    const int tid = threadIdx.x;
    const int w = tid >> 6, l = tid & 63;
    const int wr = w >> 1, wc = w & 1;
    const int e = blockIdx.x & 7;
    const int n0 = (blockIdx.x >> 3) * 32;
    const int ks0 = (blockIdx.x * 13) & 63;
    const int pos_beg = off[e], pos_end = off[e + 1];
    const char* w2b = (const char*)(w2 + (size_t)e * HDIM * IDIM);
    const char* hb  = (const char*)hbuf;

    const int ia = w * 4;                        // A instrs ia..ia+3
    const int ib = w * 2;                        // B instrs ib, ib+1
    const int arow_off = l >> 3;
    const int asw = ((l & 7) ^ (l >> 3)) << 4;
    const int brow_off = l >> 4;

    for (int m0 = pos_beg; m0 < pos_end; m0 += 128) {
        f32x4 acc[4];
#pragma unroll
        for (int i = 0; i < 4; ++i) acc[i] = (f32x4){0, 0, 0, 0};

#pragma unroll 1
        for (int it = 0; it < IDIM / 64; ++it) {
            const int ks = (it + ks0) & 63;
            const int k0 = ks * 64;
#pragma unroll
            for (int j = 0; j < 4; ++j) {
                const int i = ia + j;
                int gr = m0 + i * 8 + arow_off; if (gr > T_TOK - 1) gr = T_TOK - 1;
                gload_lds16(hb + (size_t)gr * (IDIM * 2) + k0 * 2 + asw, smem + i * 1024);
            }
#pragma unroll
            for (int j = 0; j < 2; ++j) {
                const int i = ib + j;
                const int r = i * 4 + brow_off;
                const size_t so = (size_t)(n0 + r) * (IDIM * 4) + k0 * 4 +
                                  (((l & 15) << 4) ^ ((r & 7) << 4));
                gload_lds16(w2b + so, smem + 16384 + i * 1024);
            }
            __syncthreads();

#pragma unroll
            for (int kk = 0; kk < 2; ++kk) {
                bf16x8 a[4];
#pragma unroll
                for (int fm = 0; fm < 4; ++fm) {
                    const int row = wr * 64 + fm * 16 + (l & 15);
                    const int kb = (kk * 64 + ((l >> 4) << 4)) ^ ((l & 7) << 4);
                    a[fm] = *(const bf16x8*)(smem + row * 128 + kb);
                }
                const int rB = wc * 16 + (l & 15);
                const int p0 = (kk * 128 + ((l >> 4) << 5)) ^ ((l & 7) << 4);
                const char* pb = smem + 16384 + rB * 256;
                f32x4 b0 = *(const f32x4*)(pb + p0);
                f32x4 b1 = *(const f32x4*)(pb + (p0 ^ 16));
                bf16x8 bb = cvt8(b0, b1);
#pragma unroll
                for (int fm = 0; fm < 4; ++fm)
                    acc[fm] = __builtin_amdgcn_mfma_f32_16x16x32_bf16(
                        a[fm], bb, acc[fm], 0, 0, 0);
            }
            __syncthreads();
        }

#pragma unroll
        for (int fm = 0; fm < 4; ++fm)
#pragma unroll
            for (int r = 0; r < 4; ++r) {
                const int pos = m0 + wr * 64 + fm * 16 + (l >> 4) * 4 + r;
                if (pos < pos_end) {
                    const int t = tok[pos];
                    out[(size_t)t * HDIM + n0 + wc * 16 + (l & 15)] = acc[fm][r];
                }
            }
    }
}

extern "C" void kernel_launch(void* const* d_in, const int* in_sizes, int n_in,
                              void* d_out, int out_size, void* d_ws, size_t ws_size,
                              hipStream_t stream) {
    const float* x      = (const float*)d_in[0];
    const float* logits = (const float*)d_in[1];
    const float* w1     = (const float*)d_in[2];
    const float* w3     = (const float*)d_in[3];
    const float* w2     = (const float*)d_in[4];
    float* out = (float*)d_out;

    char* ws = (char*)d_ws;
    int* off   = (int*)ws;                          // 9 ints
    int* tok   = (int*)(ws + 64);                   // 512 ints
    float* scl = (float*)(ws + 64 + 2048);          // 512 floats
    unsigned short* xs   = (unsigned short*)(ws + 8192);                             // 2 MiB
    unsigned short* hbuf = (unsigned short*)(ws + 8192 + (size_t)T_TOK * HDIM * 2);  // 4 MiB

    k_route<<<1, T_TOK, 0, stream>>>(logits, off, tok, scl);
    k_gather<<<T_TOK, 256, 0, stream>>>(x, tok, scl, xs);
    k_moe1<<<NEXP * (IDIM / 64), 512, 0, stream>>>(xs, w1, w3, off, hbuf);
    k_moe2<<<NEXP * (HDIM / 32), 256, 0, stream>>>(hbuf, w2, off, tok, out);
}